// Round 3
// baseline (718.180 us; speedup 1.0000x reference)
//
#include <hip/hip_runtime.h>
#include <hip/hip_bf16.h>

#define SEQ 2048
#define DM 2048
#define NH 16
#define HD 128
#define FF 8192

typedef float f4v __attribute__((ext_vector_type(4)));
typedef short s8v __attribute__((ext_vector_type(8)));

__device__ __forceinline__ ushort f2bf(float f) {
  unsigned int x = __float_as_uint(f);
  unsigned int r = (x + 0x7FFFu + ((x >> 16) & 1u)) >> 16;
  return (ushort)r;
}

#define AS1 __attribute__((address_space(1)))
#define AS3 __attribute__((address_space(3)))
__device__ __forceinline__ void load16_lds(const ushort* g, ushort* l) {
  __builtin_amdgcn_global_load_lds((const AS1 unsigned int*)g, (AS3 unsigned int*)l, 16, 0, 0);
}

// ---------------- fp32 -> bf16 convert ----------------
__global__ __launch_bounds__(256) void k_cvt(const float* __restrict__ in,
                                             ushort* __restrict__ out, int n4) {
  int i = blockIdx.x * 256 + threadIdx.x;
  if (i >= n4) return;
  f4v v = reinterpret_cast<const f4v*>(in)[i];
  ushort4 u;
  u.x = f2bf(v[0]); u.y = f2bf(v[1]); u.z = f2bf(v[2]); u.w = f2bf(v[3]);
  reinterpret_cast<ushort4*>(out)[i] = u;
}

// ---------------- transpose + convert: W[K][N] fp32 -> Wt[N][K] bf16 --------
__global__ __launch_bounds__(256) void k_tr(const float* __restrict__ W,
                                            ushort* __restrict__ Wt,
                                            int K, int N) {
  __shared__ float tile[32][36];
  int t = threadIdx.x;
  int n0 = blockIdx.x * 32, k0 = blockIdx.y * 32;
  int lr = t >> 3, lc = (t & 7) * 4;
  *(f4v*)&tile[lr][lc] = *(const f4v*)&W[(size_t)(k0 + lr) * N + n0 + lc];
  __syncthreads();
  int sn = t >> 3, sk = (t & 7) * 4;
  ushort4 u;
  u.x = f2bf(tile[sk + 0][sn]);
  u.y = f2bf(tile[sk + 1][sn]);
  u.z = f2bf(tile[sk + 2][sn]);
  u.w = f2bf(tile[sk + 3][sn]);
  *(ushort4*)&Wt[(size_t)(n0 + sn) * K + k0 + sk] = u;
}

// ---------------- bf16 MFMA GEMM: C = A[M][K] * Bt[N][K]^T + bias -----------
// global_load_lds (16B) staging into XOR-swizzled unpadded LDS tiles.
// LDS slot cg of row r holds global chunk cg ^ (r&7); ds_read_b128 fragment
// reads then spread over 8 distinct 4-bank groups (2-way = free).
__global__ __launch_bounds__(256) void k_gemm(const ushort* __restrict__ A,
                                              const ushort* __restrict__ Bt,
                                              const float* __restrict__ bias,
                                              float* __restrict__ Cf,
                                              ushort* __restrict__ Cb,
                                              int M, int N, int K, int gelu) {
  __shared__ ushort As[128 * 64];
  __shared__ ushort Bs[128 * 64];
  const int m0 = blockIdx.y * 128, n0 = blockIdx.x * 128;
  const int t = threadIdx.x;
  const int wave = t >> 6, lane = t & 63;
  const int wm = (wave >> 1) * 64, wn = (wave & 1) * 64;
  const int quad = lane >> 4, l16 = lane & 15;
  f4v acc[4][4] = {};
  // staging geometry: per issue, wave covers 8 rows x 8 chunks(16B)
  const int srow = lane >> 3;                 // 0..7 within issue
  const int scg = (lane & 7) ^ srow;          // swizzled global chunk
  const ushort* gA = A + (size_t)(m0 + wave * 32 + srow) * K + scg * 8;
  const ushort* gB = Bt + (size_t)(n0 + wave * 32 + srow) * K + scg * 8;
  ushort* lA = &As[(wave * 32 + srow - srow) * 64];  // wave-uniform base
  ushort* lB = &Bs[(wave * 32) * 64];
  lA = &As[(wave * 32) * 64];

  for (int k0 = 0; k0 < K; k0 += 64) {
#pragma unroll
    for (int p = 0; p < 4; ++p) {
      load16_lds(gA + (size_t)p * 8 * K + k0, lA + p * 8 * 64);
      load16_lds(gB + (size_t)p * 8 * K + k0, lB + p * 8 * 64);
    }
    __syncthreads();
#pragma unroll
    for (int kk = 0; kk < 64; kk += 32) {
      s8v af[4], bf[4];
#pragma unroll
      for (int i = 0; i < 4; ++i) {
        int ar = wm + i * 16 + l16;
        af[i] = *(const s8v*)&As[ar * 64 + ((((kk >> 3) + quad) ^ (ar & 7)) * 8)];
      }
#pragma unroll
      for (int j = 0; j < 4; ++j) {
        int br = wn + j * 16 + l16;
        bf[j] = *(const s8v*)&Bs[br * 64 + ((((kk >> 3) + quad) ^ (br & 7)) * 8)];
      }
#pragma unroll
      for (int i = 0; i < 4; ++i)
#pragma unroll
        for (int j = 0; j < 4; ++j)
          acc[i][j] = __builtin_amdgcn_mfma_f32_16x16x32_bf16(af[i], bf[j], acc[i][j], 0, 0, 0);
    }
    __syncthreads();
  }
#pragma unroll
  for (int i = 0; i < 4; ++i) {
    int rbase = m0 + wm + i * 16 + quad * 4;
#pragma unroll
    for (int j = 0; j < 4; ++j) {
      int cidx = n0 + wn + j * 16 + l16;
      float b = bias[cidx];
#pragma unroll
      for (int r = 0; r < 4; ++r) {
        float v = acc[i][j][r] + b;
        if (gelu) v = 0.5f * v * (1.0f + erff(v * 0.70710678118654752f));
        if (Cf) Cf[(size_t)(rbase + r) * N + cidx] = v;
        if (Cb) Cb[(size_t)(rbase + r) * N + cidx] = f2bf(v);
      }
    }
  }
}

// ---------------- MFMA flash attention (bf16 in/out, fp32 softmax) ----------
__global__ __launch_bounds__(256) void k_attn_mfma(const ushort* __restrict__ qkv,
                                                   ushort* __restrict__ ctx) {
  __shared__ ushort Ks[64][136];
  __shared__ ushort Vt[128][72];
  __shared__ ushort Ps[4][16][72];
  const int idx = blockIdx.x;
  const int h = idx & (NH - 1);
  const int qt = (SEQ / 64 - 1) - (idx >> 4);
  const int q0 = qt * 64;
  const int t = threadIdx.x;
  const int wave = t >> 6, lane = t & 63;
  const int quad = lane >> 4, l16 = lane & 15;
  const float scale = 0.022097086912079608f;  // 1/sqrt(2048)

  s8v aq[4];
  {
    const ushort* qp = qkv + (size_t)(q0 + 16 * wave + l16) * (3 * DM) + h * HD + quad * 8;
#pragma unroll
    for (int ks = 0; ks < 4; ++ks)
      aq[ks] = *(const s8v*)(qp + ks * 32);
  }
  f4v acc_o[8] = {};
  float m_r[4], l_r[4];
#pragma unroll
  for (int r = 0; r < 4; ++r) { m_r[r] = -1e30f; l_r[r] = 0.0f; }

  for (int kt = 0; kt <= qt; ++kt) {
    const int k0 = kt * 64;
    __syncthreads();
    {
      const ushort* kp = qkv + (size_t)k0 * (3 * DM) + DM + h * HD;
#pragma unroll
      for (int i = 0; i < 4; ++i) {
        int ch = t + i * 256;
        int row = ch >> 4, c8 = (ch & 15) * 8;
        *(s8v*)&Ks[row][c8] = *(const s8v*)(kp + (size_t)row * (3 * DM) + c8);
      }
      const ushort* vp = qkv + (size_t)k0 * (3 * DM) + 2 * DM + h * HD;
#pragma unroll
      for (int i = 0; i < 4; ++i) {
        int id = t + i * 256;
        int d = id & 127, sg = id >> 7;
        ushort e0 = vp[(size_t)(sg * 8 + 0) * (3 * DM) + d];
        ushort e1 = vp[(size_t)(sg * 8 + 1) * (3 * DM) + d];
        ushort e2 = vp[(size_t)(sg * 8 + 2) * (3 * DM) + d];
        ushort e3 = vp[(size_t)(sg * 8 + 3) * (3 * DM) + d];
        ushort e4 = vp[(size_t)(sg * 8 + 4) * (3 * DM) + d];
        ushort e5 = vp[(size_t)(sg * 8 + 5) * (3 * DM) + d];
        ushort e6 = vp[(size_t)(sg * 8 + 6) * (3 * DM) + d];
        ushort e7 = vp[(size_t)(sg * 8 + 7) * (3 * DM) + d];
        uint4 pk;
        pk.x = (uint)e0 | ((uint)e1 << 16);
        pk.y = (uint)e2 | ((uint)e3 << 16);
        pk.z = (uint)e4 | ((uint)e5 << 16);
        pk.w = (uint)e6 | ((uint)e7 << 16);
        *(uint4*)&Vt[d][sg * 8] = pk;
      }
    }
    __syncthreads();

    f4v sacc[4] = {};
#pragma unroll
    for (int ks = 0; ks < 4; ++ks) {
      s8v bk[4];
#pragma unroll
      for (int j = 0; j < 4; ++j)
        bk[j] = *(const s8v*)&Ks[j * 16 + l16][ks * 32 + quad * 8];
#pragma unroll
      for (int j = 0; j < 4; ++j)
        sacc[j] = __builtin_amdgcn_mfma_f32_16x16x32_bf16(aq[ks], bk[j], sacc[j], 0, 0, 0);
    }
    if (kt == qt) {
#pragma unroll
      for (int j = 0; j < 4; ++j)
#pragma unroll
        for (int r = 0; r < 4; ++r) {
          int lrow = 16 * wave + quad * 4 + r;
          int lcol = j * 16 + l16;
          sacc[j][r] = (lcol > lrow) ? -1e30f : sacc[j][r] * scale;
        }
    } else {
#pragma unroll
      for (int j = 0; j < 4; ++j)
#pragma unroll
        for (int r = 0; r < 4; ++r) sacc[j][r] *= scale;
    }
    float alpha[4];
#pragma unroll
    for (int r = 0; r < 4; ++r) {
      float mx = fmaxf(fmaxf(sacc[0][r], sacc[1][r]), fmaxf(sacc[2][r], sacc[3][r]));
      mx = fmaxf(mx, __shfl_xor(mx, 1));
      mx = fmaxf(mx, __shfl_xor(mx, 2));
      mx = fmaxf(mx, __shfl_xor(mx, 4));
      mx = fmaxf(mx, __shfl_xor(mx, 8));
      float mn = fmaxf(m_r[r], mx);
      alpha[r] = __expf(m_r[r] - mn);
      m_r[r] = mn;
      float ps = 0.0f;
#pragma unroll
      for (int j = 0; j < 4; ++j) {
        float p = __expf(sacc[j][r] - mn);
        sacc[j][r] = p;
        ps += p;
      }
      ps += __shfl_xor(ps, 1);
      ps += __shfl_xor(ps, 2);
      ps += __shfl_xor(ps, 4);
      ps += __shfl_xor(ps, 8);
      l_r[r] = l_r[r] * alpha[r] + ps;
    }
#pragma unroll
    for (int j = 0; j < 4; ++j)
#pragma unroll
      for (int r = 0; r < 4; ++r)
        Ps[wave][quad * 4 + r][j * 16 + l16] = f2bf(sacc[j][r]);
#pragma unroll
    for (int nd = 0; nd < 8; ++nd)
#pragma unroll
      for (int r = 0; r < 4; ++r) acc_o[nd][r] *= alpha[r];
#pragma unroll
    for (int ks2 = 0; ks2 < 2; ++ks2) {
      s8v ap = *(const s8v*)&Ps[wave][l16][ks2 * 32 + quad * 8];
#pragma unroll
      for (int nd = 0; nd < 8; ++nd) {
        s8v bv = *(const s8v*)&Vt[nd * 16 + l16][ks2 * 32 + quad * 8];
        acc_o[nd] = __builtin_amdgcn_mfma_f32_16x16x32_bf16(ap, bv, acc_o[nd], 0, 0, 0);
      }
    }
  }
  float rl[4];
#pragma unroll
  for (int r = 0; r < 4; ++r) rl[r] = 1.0f / l_r[r];
#pragma unroll
  for (int nd = 0; nd < 8; ++nd) {
    int col = h * HD + nd * 16 + l16;
#pragma unroll
    for (int r = 0; r < 4; ++r) {
      int row = q0 + 16 * wave + quad * 4 + r;
      ctx[(size_t)row * DM + col] = f2bf(acc_o[nd][r] * rl[r]);
    }
  }
}

// ---------------- layernorm(a + b): fp32 out + optional bf16 out ------------
__global__ __launch_bounds__(256) void k_ln(const float* __restrict__ A,
                                            const float* __restrict__ B,
                                            const float* __restrict__ g,
                                            const float* __restrict__ be,
                                            float* __restrict__ outf,
                                            ushort* __restrict__ outb) {
  int row = blockIdx.x;
  int t = threadIdx.x;
  const f4v* av = reinterpret_cast<const f4v*>(A + (size_t)row * DM);
  const f4v* bv = reinterpret_cast<const f4v*>(B + (size_t)row * DM);
  f4v x0 = av[t] + bv[t];
  f4v x1 = av[t + 256] + bv[t + 256];
  float s = x0[0] + x0[1] + x0[2] + x0[3] + x1[0] + x1[1] + x1[2] + x1[3];
  float q = x0[0]*x0[0] + x0[1]*x0[1] + x0[2]*x0[2] + x0[3]*x0[3]
          + x1[0]*x1[0] + x1[1]*x1[1] + x1[2]*x1[2] + x1[3]*x1[3];
#pragma unroll
  for (int off = 32; off; off >>= 1) {
    s += __shfl_down(s, off, 64);
    q += __shfl_down(q, off, 64);
  }
  __shared__ float rs[4], rq[4];
  if ((t & 63) == 0) { rs[t >> 6] = s; rq[t >> 6] = q; }
  __syncthreads();
  s = rs[0] + rs[1] + rs[2] + rs[3];
  q = rq[0] + rq[1] + rq[2] + rq[3];
  float mu = s * (1.0f / DM);
  float var = q * (1.0f / DM) - mu * mu;
  float rstd = rsqrtf(var + 1e-5f);
  const f4v* gv = reinterpret_cast<const f4v*>(g);
  const f4v* bev = reinterpret_cast<const f4v*>(be);
  f4v y0 = (x0 - mu) * rstd * gv[t] + bev[t];
  f4v y1 = (x1 - mu) * rstd * gv[t + 256] + bev[t + 256];
  reinterpret_cast<f4v*>(outf + (size_t)row * DM)[t] = y0;
  reinterpret_cast<f4v*>(outf + (size_t)row * DM)[t + 256] = y1;
  if (outb) {
    ushort4 u0, u1;
    u0.x = f2bf(y0[0]); u0.y = f2bf(y0[1]); u0.z = f2bf(y0[2]); u0.w = f2bf(y0[3]);
    u1.x = f2bf(y1[0]); u1.y = f2bf(y1[1]); u1.z = f2bf(y1[2]); u1.w = f2bf(y1[3]);
    reinterpret_cast<ushort4*>(outb + (size_t)row * DM)[t] = u0;
    reinterpret_cast<ushort4*>(outb + (size_t)row * DM)[t + 256] = u1;
  }
}

extern "C" void kernel_launch(void* const* d_in, const int* in_sizes, int n_in,
                              void* d_out, int out_size, void* d_ws, size_t ws_size,
                              hipStream_t stream) {
  const float* x     = (const float*)d_in[0];
  const float* C_w   = (const float*)d_in[1];
  const float* C_b   = (const float*)d_in[2];
  const float* lin_w = (const float*)d_in[3];
  const float* lin_b = (const float*)d_in[4];
  const float* ff1_w = (const float*)d_in[5];
  const float* ff1_b = (const float*)d_in[6];
  const float* ff2_w = (const float*)d_in[7];
  const float* ff2_b = (const float*)d_in[8];
  const float* ln1g  = (const float*)d_in[9];
  const float* ln1b  = (const float*)d_in[10];
  const float* ln2g  = (const float*)d_in[11];
  const float* ln2b  = (const float*)d_in[12];

  char* ws = (char*)d_ws;
  size_t off = 0;
  auto take = [&](size_t bytes) {
    char* p = ws + off;
    off += (bytes + 255) & ~(size_t)255;
    return p;
  };
  ushort* Wt   = (ushort*)take((size_t)FF * DM * 2);
  ushort* qkvb = (ushort*)take((size_t)SEQ * 3 * DM * 2);
  ushort* xb   = (ushort*)take((size_t)SEQ * DM * 2);
  ushort* ctxb = (ushort*)take((size_t)SEQ * DM * 2);
  ushort* bigb = (ushort*)take((size_t)SEQ * FF * 2);
  float*  attn = (float*) take((size_t)SEQ * DM * 4);
  float*  h1   = (float*) take((size_t)SEQ * DM * 4);
  float*  ff2o = (float*) take((size_t)SEQ * DM * 4);

  k_cvt<<<SEQ * DM / 1024, 256, 0, stream>>>(x, xb, SEQ * DM / 4);
  k_tr<<<dim3(3 * DM / 32, DM / 32), 256, 0, stream>>>(C_w, Wt, DM, 3 * DM);
  k_gemm<<<dim3(3 * DM / 128, SEQ / 128), 256, 0, stream>>>(xb, Wt, C_b, nullptr, qkvb, SEQ, 3 * DM, DM, 0);
  k_attn_mfma<<<dim3((SEQ / 64) * NH), 256, 0, stream>>>(qkvb, ctxb);
  k_tr<<<dim3(DM / 32, DM / 32), 256, 0, stream>>>(lin_w, Wt, DM, DM);
  k_gemm<<<dim3(DM / 128, SEQ / 128), 256, 0, stream>>>(ctxb, Wt, lin_b, attn, nullptr, SEQ, DM, DM, 0);
  k_ln<<<SEQ, 256, 0, stream>>>(x, attn, ln1g, ln1b, h1, xb);
  k_tr<<<dim3(FF / 32, DM / 32), 256, 0, stream>>>(ff1_w, Wt, DM, FF);
  k_gemm<<<dim3(FF / 128, SEQ / 128), 256, 0, stream>>>(xb, Wt, ff1_b, nullptr, bigb, SEQ, FF, DM, 1);
  k_tr<<<dim3(DM / 32, FF / 32), 256, 0, stream>>>(ff2_w, Wt, FF, DM);
  k_gemm<<<dim3(DM / 128, SEQ / 128), 256, 0, stream>>>(bigb, Wt, ff2_b, ff2o, nullptr, SEQ, DM, FF, 0);
  k_ln<<<SEQ, 256, 0, stream>>>(h1, ff2o, ln2g, ln2b, (float*)d_out, (ushort*)nullptr);
}

// Round 4
// 651.773 us; speedup vs baseline: 1.1019x; 1.1019x over previous
//
#include <hip/hip_runtime.h>
#include <hip/hip_bf16.h>

#define SEQ 2048
#define DM 2048
#define NH 16
#define HD 128
#define FF 8192

typedef float f4v __attribute__((ext_vector_type(4)));
typedef short s8v __attribute__((ext_vector_type(8)));

__device__ __forceinline__ ushort f2bf(float f) {
  unsigned int x = __float_as_uint(f);
  unsigned int r = (x + 0x7FFFu + ((x >> 16) & 1u)) >> 16;
  return (ushort)r;
}

#define AS1 __attribute__((address_space(1)))
#define AS3 __attribute__((address_space(3)))
__device__ __forceinline__ void load16_lds(const ushort* g, ushort* l) {
  __builtin_amdgcn_global_load_lds((const AS1 unsigned int*)g, (AS3 unsigned int*)l, 16, 0, 0);
}

// ---------------- fp32 -> bf16 convert ----------------
__global__ __launch_bounds__(256) void k_cvt(const float* __restrict__ in,
                                             ushort* __restrict__ out, int n4) {
  int i = blockIdx.x * 256 + threadIdx.x;
  if (i >= n4) return;
  f4v v = reinterpret_cast<const f4v*>(in)[i];
  ushort4 u;
  u.x = f2bf(v[0]); u.y = f2bf(v[1]); u.z = f2bf(v[2]); u.w = f2bf(v[3]);
  reinterpret_cast<ushort4*>(out)[i] = u;
}

// ---------------- transpose + convert: W[K][N] fp32 -> Wt[N][K] bf16 --------
__global__ __launch_bounds__(256) void k_tr(const float* __restrict__ W,
                                            ushort* __restrict__ Wt,
                                            int K, int N) {
  __shared__ float tile[32][36];
  int t = threadIdx.x;
  int n0 = blockIdx.x * 32, k0 = blockIdx.y * 32;
  int lr = t >> 3, lc = (t & 7) * 4;
  *(f4v*)&tile[lr][lc] = *(const f4v*)&W[(size_t)(k0 + lr) * N + n0 + lc];
  __syncthreads();
  int sn = t >> 3, sk = (t & 7) * 4;
  ushort4 u;
  u.x = f2bf(tile[sk + 0][sn]);
  u.y = f2bf(tile[sk + 1][sn]);
  u.z = f2bf(tile[sk + 2][sn]);
  u.w = f2bf(tile[sk + 3][sn]);
  *(ushort4*)&Wt[(size_t)(n0 + sn) * K + k0 + sk] = u;
}

// ---------------- bf16 MFMA GEMM: C = A[M][K] * Bt[N][K]^T (+bias/gelu) -----
// Split-K via gridDim.z: block z handles K-chunk z, writes fp32 partial at
// Cf + z*M*N (bias must be null for split). global_load_lds 16B staging into
// XOR-swizzled unpadded LDS (slot cg of row r holds global chunk cg^(r&7)).
__global__ __launch_bounds__(256) void k_gemm(const ushort* __restrict__ A,
                                              const ushort* __restrict__ Bt,
                                              const float* __restrict__ bias,
                                              float* __restrict__ Cf,
                                              ushort* __restrict__ Cb,
                                              int M, int N, int K, int gelu) {
  __shared__ ushort As[128 * 64];
  __shared__ ushort Bs[128 * 64];
  const int m0 = blockIdx.y * 128, n0 = blockIdx.x * 128;
  const int t = threadIdx.x;
  const int wave = t >> 6, lane = t & 63;
  const int wm = (wave >> 1) * 64, wn = (wave & 1) * 64;
  const int quad = lane >> 4, l16 = lane & 15;
  const int kchunk = K / gridDim.z;
  const int kbeg = blockIdx.z * kchunk, kend = kbeg + kchunk;
  if (Cf && gridDim.z > 1) Cf += (size_t)blockIdx.z * M * N;
  f4v acc[4][4] = {};
  const int srow = lane >> 3;                 // 0..7 within issue
  const int scg = (lane & 7) ^ srow;          // swizzled global chunk
  const ushort* gA = A + (size_t)(m0 + wave * 32 + srow) * K + scg * 8;
  const ushort* gB = Bt + (size_t)(n0 + wave * 32 + srow) * K + scg * 8;
  ushort* lA = &As[(wave * 32) * 64];
  ushort* lB = &Bs[(wave * 32) * 64];

  for (int k0 = kbeg; k0 < kend; k0 += 64) {
#pragma unroll
    for (int p = 0; p < 4; ++p) {
      load16_lds(gA + (size_t)p * 8 * K + k0, lA + p * 8 * 64);
      load16_lds(gB + (size_t)p * 8 * K + k0, lB + p * 8 * 64);
    }
    __syncthreads();
#pragma unroll
    for (int kk = 0; kk < 64; kk += 32) {
      s8v af[4], bf[4];
#pragma unroll
      for (int i = 0; i < 4; ++i) {
        int ar = wm + i * 16 + l16;
        af[i] = *(const s8v*)&As[ar * 64 + ((((kk >> 3) + quad) ^ (ar & 7)) * 8)];
      }
#pragma unroll
      for (int j = 0; j < 4; ++j) {
        int br = wn + j * 16 + l16;
        bf[j] = *(const s8v*)&Bs[br * 64 + ((((kk >> 3) + quad) ^ (br & 7)) * 8)];
      }
#pragma unroll
      for (int i = 0; i < 4; ++i)
#pragma unroll
        for (int j = 0; j < 4; ++j)
          acc[i][j] = __builtin_amdgcn_mfma_f32_16x16x32_bf16(af[i], bf[j], acc[i][j], 0, 0, 0);
    }
    __syncthreads();
  }
#pragma unroll
  for (int i = 0; i < 4; ++i) {
    int rbase = m0 + wm + i * 16 + quad * 4;
#pragma unroll
    for (int j = 0; j < 4; ++j) {
      int cidx = n0 + wn + j * 16 + l16;
      float b = bias ? bias[cidx] : 0.0f;
#pragma unroll
      for (int r = 0; r < 4; ++r) {
        float v = acc[i][j][r] + b;
        if (gelu) v = 0.5f * v * (1.0f + erff(v * 0.70710678118654752f));
        if (Cf) Cf[(size_t)(rbase + r) * N + cidx] = v;
        if (Cb) Cb[(size_t)(rbase + r) * N + cidx] = f2bf(v);
      }
    }
  }
}

// ---------------- MFMA flash attention (bf16 in/out, fp32 softmax) ----------
__global__ __launch_bounds__(256) void k_attn_mfma(const ushort* __restrict__ qkv,
                                                   ushort* __restrict__ ctx) {
  __shared__ ushort Ks[64][136];
  __shared__ ushort Vt[128][72];
  __shared__ ushort Ps[4][16][72];
  const int idx = blockIdx.x;
  const int h = idx & (NH - 1);
  const int qt = (SEQ / 64 - 1) - (idx >> 4);
  const int q0 = qt * 64;
  const int t = threadIdx.x;
  const int wave = t >> 6, lane = t & 63;
  const int quad = lane >> 4, l16 = lane & 15;
  const float scale = 0.022097086912079608f;  // 1/sqrt(2048)

  s8v aq[4];
  {
    const ushort* qp = qkv + (size_t)(q0 + 16 * wave + l16) * (3 * DM) + h * HD + quad * 8;
#pragma unroll
    for (int ks = 0; ks < 4; ++ks)
      aq[ks] = *(const s8v*)(qp + ks * 32);
  }
  f4v acc_o[8] = {};
  float m_r[4], l_r[4];
#pragma unroll
  for (int r = 0; r < 4; ++r) { m_r[r] = -1e30f; l_r[r] = 0.0f; }

  for (int kt = 0; kt <= qt; ++kt) {
    const int k0 = kt * 64;
    __syncthreads();
    {
      const ushort* kp = qkv + (size_t)k0 * (3 * DM) + DM + h * HD;
#pragma unroll
      for (int i = 0; i < 4; ++i) {
        int ch = t + i * 256;
        int row = ch >> 4, c8 = (ch & 15) * 8;
        *(s8v*)&Ks[row][c8] = *(const s8v*)(kp + (size_t)row * (3 * DM) + c8);
      }
      const ushort* vp = qkv + (size_t)k0 * (3 * DM) + 2 * DM + h * HD;
#pragma unroll
      for (int i = 0; i < 4; ++i) {
        int id = t + i * 256;
        int d = id & 127, sg = id >> 7;
        ushort e0 = vp[(size_t)(sg * 8 + 0) * (3 * DM) + d];
        ushort e1 = vp[(size_t)(sg * 8 + 1) * (3 * DM) + d];
        ushort e2 = vp[(size_t)(sg * 8 + 2) * (3 * DM) + d];
        ushort e3 = vp[(size_t)(sg * 8 + 3) * (3 * DM) + d];
        ushort e4 = vp[(size_t)(sg * 8 + 4) * (3 * DM) + d];
        ushort e5 = vp[(size_t)(sg * 8 + 5) * (3 * DM) + d];
        ushort e6 = vp[(size_t)(sg * 8 + 6) * (3 * DM) + d];
        ushort e7 = vp[(size_t)(sg * 8 + 7) * (3 * DM) + d];
        uint4 pk;
        pk.x = (uint)e0 | ((uint)e1 << 16);
        pk.y = (uint)e2 | ((uint)e3 << 16);
        pk.z = (uint)e4 | ((uint)e5 << 16);
        pk.w = (uint)e6 | ((uint)e7 << 16);
        *(uint4*)&Vt[d][sg * 8] = pk;
      }
    }
    __syncthreads();

    f4v sacc[4] = {};
#pragma unroll
    for (int ks = 0; ks < 4; ++ks) {
      s8v bk[4];
#pragma unroll
      for (int j = 0; j < 4; ++j)
        bk[j] = *(const s8v*)&Ks[j * 16 + l16][ks * 32 + quad * 8];
#pragma unroll
      for (int j = 0; j < 4; ++j)
        sacc[j] = __builtin_amdgcn_mfma_f32_16x16x32_bf16(aq[ks], bk[j], sacc[j], 0, 0, 0);
    }
    if (kt == qt) {
#pragma unroll
      for (int j = 0; j < 4; ++j)
#pragma unroll
        for (int r = 0; r < 4; ++r) {
          int lrow = 16 * wave + quad * 4 + r;
          int lcol = j * 16 + l16;
          sacc[j][r] = (lcol > lrow) ? -1e30f : sacc[j][r] * scale;
        }
    } else {
#pragma unroll
      for (int j = 0; j < 4; ++j)
#pragma unroll
        for (int r = 0; r < 4; ++r) sacc[j][r] *= scale;
    }
    float alpha[4];
#pragma unroll
    for (int r = 0; r < 4; ++r) {
      float mx = fmaxf(fmaxf(sacc[0][r], sacc[1][r]), fmaxf(sacc[2][r], sacc[3][r]));
      mx = fmaxf(mx, __shfl_xor(mx, 1));
      mx = fmaxf(mx, __shfl_xor(mx, 2));
      mx = fmaxf(mx, __shfl_xor(mx, 4));
      mx = fmaxf(mx, __shfl_xor(mx, 8));
      float mn = fmaxf(m_r[r], mx);
      alpha[r] = __expf(m_r[r] - mn);
      m_r[r] = mn;
      float ps = 0.0f;
#pragma unroll
      for (int j = 0; j < 4; ++j) {
        float p = __expf(sacc[j][r] - mn);
        sacc[j][r] = p;
        ps += p;
      }
      ps += __shfl_xor(ps, 1);
      ps += __shfl_xor(ps, 2);
      ps += __shfl_xor(ps, 4);
      ps += __shfl_xor(ps, 8);
      l_r[r] = l_r[r] * alpha[r] + ps;
    }
#pragma unroll
    for (int j = 0; j < 4; ++j)
#pragma unroll
      for (int r = 0; r < 4; ++r)
        Ps[wave][quad * 4 + r][j * 16 + l16] = f2bf(sacc[j][r]);
#pragma unroll
    for (int nd = 0; nd < 8; ++nd)
#pragma unroll
      for (int r = 0; r < 4; ++r) acc_o[nd][r] *= alpha[r];
#pragma unroll
    for (int ks2 = 0; ks2 < 2; ++ks2) {
      s8v ap = *(const s8v*)&Ps[wave][l16][ks2 * 32 + quad * 8];
#pragma unroll
      for (int nd = 0; nd < 8; ++nd) {
        s8v bv = *(const s8v*)&Vt[nd * 16 + l16][ks2 * 32 + quad * 8];
        acc_o[nd] = __builtin_amdgcn_mfma_f32_16x16x32_bf16(ap, bv, acc_o[nd], 0, 0, 0);
      }
    }
  }
  float rl[4];
#pragma unroll
  for (int r = 0; r < 4; ++r) rl[r] = 1.0f / l_r[r];
#pragma unroll
  for (int nd = 0; nd < 8; ++nd) {
    int col = h * HD + nd * 16 + l16;
#pragma unroll
    for (int r = 0; r < 4; ++r) {
      int row = q0 + 16 * wave + quad * 4 + r;
      ctx[(size_t)row * DM + col] = f2bf(acc_o[nd][r] * rl[r]);
    }
  }
}

// -------- layernorm(A + sum(partials) + bias): fp32 out + optional bf16 ----
__global__ __launch_bounds__(256) void k_ln_sk(const float* __restrict__ A,
                                               const float* __restrict__ P, int np,
                                               const float* __restrict__ bias,
                                               const float* __restrict__ g,
                                               const float* __restrict__ be,
                                               float* __restrict__ outf,
                                               ushort* __restrict__ outb) {
  int row = blockIdx.x;
  int t = threadIdx.x;
  const f4v* av = reinterpret_cast<const f4v*>(A + (size_t)row * DM);
  f4v x0 = av[t];
  f4v x1 = av[t + 256];
  for (int s = 0; s < np; ++s) {
    const f4v* pv = reinterpret_cast<const f4v*>(P + (size_t)s * SEQ * DM + (size_t)row * DM);
    x0 += pv[t];
    x1 += pv[t + 256];
  }
  const f4v* bb = reinterpret_cast<const f4v*>(bias);
  x0 += bb[t];
  x1 += bb[t + 256];
  float s = x0[0] + x0[1] + x0[2] + x0[3] + x1[0] + x1[1] + x1[2] + x1[3];
  float q = x0[0]*x0[0] + x0[1]*x0[1] + x0[2]*x0[2] + x0[3]*x0[3]
          + x1[0]*x1[0] + x1[1]*x1[1] + x1[2]*x1[2] + x1[3]*x1[3];
#pragma unroll
  for (int off = 32; off; off >>= 1) {
    s += __shfl_down(s, off, 64);
    q += __shfl_down(q, off, 64);
  }
  __shared__ float rs[4], rq[4];
  if ((t & 63) == 0) { rs[t >> 6] = s; rq[t >> 6] = q; }
  __syncthreads();
  s = rs[0] + rs[1] + rs[2] + rs[3];
  q = rq[0] + rq[1] + rq[2] + rq[3];
  float mu = s * (1.0f / DM);
  float var = q * (1.0f / DM) - mu * mu;
  float rstd = rsqrtf(var + 1e-5f);
  const f4v* gv = reinterpret_cast<const f4v*>(g);
  const f4v* bev = reinterpret_cast<const f4v*>(be);
  f4v y0 = (x0 - mu) * rstd * gv[t] + bev[t];
  f4v y1 = (x1 - mu) * rstd * gv[t + 256] + bev[t + 256];
  reinterpret_cast<f4v*>(outf + (size_t)row * DM)[t] = y0;
  reinterpret_cast<f4v*>(outf + (size_t)row * DM)[t + 256] = y1;
  if (outb) {
    ushort4 u0, u1;
    u0.x = f2bf(y0[0]); u0.y = f2bf(y0[1]); u0.z = f2bf(y0[2]); u0.w = f2bf(y0[3]);
    u1.x = f2bf(y1[0]); u1.y = f2bf(y1[1]); u1.z = f2bf(y1[2]); u1.w = f2bf(y1[3]);
    reinterpret_cast<ushort4*>(outb + (size_t)row * DM)[t] = u0;
    reinterpret_cast<ushort4*>(outb + (size_t)row * DM)[t + 256] = u1;
  }
}

extern "C" void kernel_launch(void* const* d_in, const int* in_sizes, int n_in,
                              void* d_out, int out_size, void* d_ws, size_t ws_size,
                              hipStream_t stream) {
  const float* x     = (const float*)d_in[0];
  const float* C_w   = (const float*)d_in[1];
  const float* C_b   = (const float*)d_in[2];
  const float* lin_w = (const float*)d_in[3];
  const float* lin_b = (const float*)d_in[4];
  const float* ff1_w = (const float*)d_in[5];
  const float* ff1_b = (const float*)d_in[6];
  const float* ff2_w = (const float*)d_in[7];
  const float* ff2_b = (const float*)d_in[8];
  const float* ln1g  = (const float*)d_in[9];
  const float* ln1b  = (const float*)d_in[10];
  const float* ln2g  = (const float*)d_in[11];
  const float* ln2b  = (const float*)d_in[12];

  char* ws = (char*)d_ws;
  size_t off = 0;
  auto take = [&](size_t bytes) {
    char* p = ws + off;
    off += (bytes + 255) & ~(size_t)255;
    return p;
  };
  ushort* Wt   = (ushort*)take((size_t)FF * DM * 2);      // 33.6 MB
  ushort* qkvb = (ushort*)take((size_t)SEQ * 3 * DM * 2); // 25.2 MB
  ushort* xb   = (ushort*)take((size_t)SEQ * DM * 2);     //  8.4 MB
  ushort* ctxb = (ushort*)take((size_t)SEQ * DM * 2);     //  8.4 MB
  ushort* bigb = (ushort*)take((size_t)SEQ * FF * 2);     // 33.6 MB
  float*  h1   = (float*) take((size_t)SEQ * DM * 4);     // 16.8 MB
  float*  part = (float*) take((size_t)4 * SEQ * DM * 4); // 67.1 MB split-K partials

  k_cvt<<<SEQ * DM / 1024, 256, 0, stream>>>(x, xb, SEQ * DM / 4);
  // qkv = x @ C_w + C_b (bf16 out)
  k_tr<<<dim3(3 * DM / 32, DM / 32), 256, 0, stream>>>(C_w, Wt, DM, 3 * DM);
  k_gemm<<<dim3(3 * DM / 128, SEQ / 128, 1), 256, 0, stream>>>(xb, Wt, C_b, nullptr, qkvb, SEQ, 3 * DM, DM, 0);
  // causal MFMA flash attention -> ctxb (bf16)
  k_attn_mfma<<<dim3((SEQ / 64) * NH), 256, 0, stream>>>(qkvb, ctxb);
  // proj partials: ctx @ lin_w, split-K=4 (bias folded into LN1)
  k_tr<<<dim3(DM / 32, DM / 32), 256, 0, stream>>>(lin_w, Wt, DM, DM);
  k_gemm<<<dim3(DM / 128, SEQ / 128, 4), 256, 0, stream>>>(ctxb, Wt, nullptr, part, nullptr, SEQ, DM, DM, 0);
  // h1 = LN(x + sum(part) + lin_b); bf16 copy -> xb
  k_ln_sk<<<SEQ, 256, 0, stream>>>(x, part, 4, lin_b, ln1g, ln1b, h1, xb);
  // ff1 = gelu(h1 @ ff1_w + ff1_b) (bf16 out)
  k_tr<<<dim3(FF / 32, DM / 32), 256, 0, stream>>>(ff1_w, Wt, DM, FF);
  k_gemm<<<dim3(FF / 128, SEQ / 128, 1), 256, 0, stream>>>(xb, Wt, ff1_b, nullptr, bigb, SEQ, FF, DM, 1);
  // ff2 partials: gelu(ff1) @ ff2_w, split-K=4 (bias folded into LN2)
  k_tr<<<dim3(DM / 32, FF / 32), 256, 0, stream>>>(ff2_w, Wt, FF, DM);
  k_gemm<<<dim3(DM / 128, SEQ / 128, 4), 256, 0, stream>>>(bigb, Wt, nullptr, part, nullptr, SEQ, DM, FF, 0);
  // out = LN(h1 + sum(part) + ff2_b)
  k_ln_sk<<<SEQ, 256, 0, stream>>>(h1, part, 4, ff2_b, ln2g, ln2b, (float*)d_out, (ushort*)nullptr);
}